// Round 14
// baseline (14467.125 us; speedup 1.0000x reference)
//
#include <hip/hip_runtime.h>

typedef _Float16 f16;
typedef _Float16 f16x2 __attribute__((ext_vector_type(2)));
typedef _Float16 f16x4 __attribute__((ext_vector_type(4)));
typedef _Float16 f16x8 __attribute__((ext_vector_type(8)));
typedef float    f32x4 __attribute__((ext_vector_type(4)));

#define TT   512
#define BB   64
#define DD   512
#define HH   1024
#define H2   2048
#define NR_  64
#define NH_  8
#define HD_  128
#define MROWS (TT*BB)      // 32768
#define RWG  64            // recurrence workgroups

#define ALOAD32(p)   __hip_atomic_load((p),  __ATOMIC_RELAXED, __HIP_MEMORY_SCOPE_AGENT)
#define ASTORE(p,v)  __hip_atomic_store((p), (v), __ATOMIC_RELAXED, __HIP_MEMORY_SCOPE_AGENT)

// ---------------- prep kernels ----------------
__global__ void k_cvt(const float* __restrict__ s, f16* __restrict__ d, int n) {
  int i = blockIdx.x * blockDim.x + threadIdx.x;
  int st = gridDim.x * blockDim.x;
  for (; i < n; i += st) d[i] = (f16)s[i];
}

__global__ void k_scatter(const float* __restrict__ x, const int* __restrict__ idx,
                          f16* __restrict__ xpad, int total) {
  int i = blockIdx.x * blockDim.x + threadIdx.x;
  int st = gridDim.x * blockDim.x;
  int n = total * DD;
  for (; i < n; i += st) {
    int p = i >> 9;          // / DD
    int j = i & (DD - 1);
    xpad[(size_t)idx[p] * DD + j] = (f16)x[i];
  }
}

__global__ void k_inv(const int* __restrict__ idx, int* __restrict__ inv, int total) {
  int i = blockIdx.x * blockDim.x + threadIdx.x;
  if (i < total) inv[idx[i]] = i;
}

// ---------------- fp16 GEMM: C[m,n] = sum_k A[m,k]*Bw[n,k] + bias[n] ----------------
__global__ __launch_bounds__(256)
void k_gemm(const f16* __restrict__ A, const f16* __restrict__ Bw,
            const float* __restrict__ bias, f16* __restrict__ C,
            int N, int K, int Mvalid) {
  __shared__ __align__(16) f16 As[128 * 32];
  __shared__ __align__(16) f16 Bs[128 * 32];
  const int tid  = threadIdx.x;
  const int lane = tid & 63;
  const int wave = tid >> 6;
  const int m0 = blockIdx.y * 128;
  const int n0 = blockIdx.x * 128;
  const int mw = (wave >> 1) * 64;
  const int nw = (wave & 1) * 64;
  const int NT = K >> 5;
  const int c0 = tid * 2;

  float4 pa[2], pb[2];
  auto fetch = [&](int kt) {
#pragma unroll
    for (int i = 0; i < 2; ++i) {
      int c = c0 + i;
      int row = c >> 2, kc = c & 3;
      pa[i] = *(const float4*)&A [(size_t)(m0 + row) * K + kt * 32 + kc * 8];
      pb[i] = *(const float4*)&Bw[(size_t)(n0 + row) * K + kt * 32 + kc * 8];
    }
  };

  f32x4 acc[4][4] = {};
  fetch(0);
  for (int kt = 0; kt < NT; ++kt) {
    __syncthreads();
#pragma unroll
    for (int i = 0; i < 2; ++i) {
      int c = c0 + i;
      *(float4*)&As[c * 8] = pa[i];
      *(float4*)&Bs[c * 8] = pb[i];
    }
    __syncthreads();
    if (kt + 1 < NT) fetch(kt + 1);
    f16x8 af[4], bf[4];
#pragma unroll
    for (int i = 0; i < 4; ++i) {
      af[i] = *(const f16x8*)&As[(mw + i * 16 + (lane & 15)) * 32 + (lane >> 4) * 8];
      bf[i] = *(const f16x8*)&Bs[(nw + i * 16 + (lane & 15)) * 32 + (lane >> 4) * 8];
    }
#pragma unroll
    for (int i = 0; i < 4; ++i)
#pragma unroll
      for (int j = 0; j < 4; ++j)
        acc[i][j] = __builtin_amdgcn_mfma_f32_16x16x32_f16(af[i], bf[j], acc[i][j], 0, 0, 0);
  }

#pragma unroll
  for (int j = 0; j < 4; ++j) {
    int col = n0 + nw + j * 16 + (lane & 15);
    float bv = bias[col];
#pragma unroll
    for (int i = 0; i < 4; ++i) {
#pragma unroll
      for (int r = 0; r < 4; ++r) {
        int row = m0 + mw + i * 16 + (lane >> 4) * 4 + r;
        if (row < Mvalid) C[(size_t)row * N + col] = (f16)(acc[i][j][r] + bv);
      }
    }
  }
}

// ---------------- persistent recurrence kernel (per-WAVE dataflow flags) ----------------
// r11 skeleton (PASSED) with per-wave flag publication: each wave drains its own
// stores (s_waitcnt vmcnt(0)) and posts Afl/Bfl[wg*8+wave] — no wg rendezvous
// before flags. The single pbuf __syncthreads per step remains, and carries the
// overwrite-safety proof: fg(t) stores occur AFTER it, and entry to it requires
// both kh-halves' h-waits (jointly all 64 wgs' Bfl >= t-1) => all B(t-1) fg
// reads complete before any fg(t) store. h parity double-buffer as in r11.
// Phase A: wg = col-slice cs (32 cols, full K); wave = (rt 0..3, kh 0..1):
//   waits 256 producer-wave flags of its K-half, K-half h-load (16B sc0/sc1),
//   MFMA, parity-pbuf half-K reduction, fg stores, own-wave flag.
// Phase B: wave <-> (b, nh): waits its 16 exact fg-producer waves, softmax-bind,
//   h store (parity t&1), own-wave flag, overlapped output writes.
__global__ __launch_bounds__(512, 2)
void k_rec(const f16* __restrict__ Wh16, const float* __restrict__ bh,
           const f16* __restrict__ v16,  const f16* __restrict__ x2fg,
           f16* __restrict__ hfrag, float* __restrict__ fgbuf,
           f16* __restrict__ hs_out, float* __restrict__ out_packed,
           float* __restrict__ hn_out,
           const int* __restrict__ inv, const int* __restrict__ lgt,
           int* __restrict__ Afl, int* __restrict__ Bfl, int epoch0)
{
  __shared__ __align__(16) f16   Wlds[32 * 2 * 64 * 8];  // 64 KB [kk][ct][lane][8]
  __shared__ __align__(16) f16x4 Rq[32 * 64];            // 16 KB
  __shared__ __align__(16) f16x4 Uq[16 * 2 * 64];        // 16 KB
  __shared__ __align__(16) f32x4 pbuf[2][8][64];         // 16 KB: parity half-K partials
  __shared__ __align__(16) float fbuf[8][128];           // 4 KB (wave-private rows)
  __shared__ __align__(16) float abuf[8][64];            // 2 KB (wave-private rows)

  const int tid  = threadIdx.x;
  const int lane = tid & 63;
  const int wave = tid >> 6;
  const int wg   = blockIdx.x;
  const int cs   = wg;                   // col-slice: cols cs*32 .. cs*32+32
  const int rt   = wave & 3;             // row tile 0..3
  const int kh   = wave >> 2;            // K-half 0/1
  const int nh   = wg >> 3;
  const int b    = ((wg & 7) << 3) + wave;
  const int cf   = nh * HD_;

  // stage full-K Wh slice (32 cols) into LDS in MFMA B-fragment layout
  for (int i = tid; i < 32 * 2 * 64; i += 512) {
    int kk = i >> 7;
    int nt = (i >> 6) & 1;
    int ln = i & 63;
    int col = cs * 32 + nt * 16 + (ln & 15);
    int kg  = kk * 32 + (ln >> 4) * 8;
    *(float4*)&Wlds[(size_t)i * 8] = *(const float4*)&Wh16[(size_t)col * HH + kg];
  }
  // role basis -> LDS
  for (int e = tid; e < 32 * 64; e += 512) {
    int i = e >> 6, role = e & 63;
    Rq[e] = *(const f16x4*)&v16[(size_t)role * H2 + nh * 256 + 4 * i];
  }
  // unbind basis -> LDS
  for (int e = tid; e < 16 * 2 * 64; e += 512) {
    int i = e >> 7, half = (e >> 6) & 1, l = e & 63;
    int r0 = 4 * i + 2 * half;
    const f16* u0 = &v16[(size_t)r0 * H2 + nh * 256 + 128 + 2 * l];
    const f16* u1 = &v16[(size_t)(r0 + 1) * H2 + nh * 256 + 128 + 2 * l];
    f16x4 tv; tv.x = u0[0]; tv.y = u0[1]; tv.z = u1[0]; tv.w = u1[1];
    Uq[e] = tv;
  }
  __syncthreads();

  const int d0 = cf + 2 * lane;
  const float2 bf2 = *(const float2*)&bh[d0];
  const float2 bg2 = *(const float2*)&bh[HH + d0];
  const int lb = lgt[b];
  float ho0 = 0.f, ho1 = 0.f;
  const int myf = wg * 8 + wave;         // this wave's flag slot
  // fg producer waves for (b, nh): 8 wgs x (kh 0/1) with rt = b>>4 -> 16 flags
  const int rtb = b >> 4;
  int widx;
  {
    int j = lane & 3, gsel = (lane >> 2) & 1, khp = (lane >> 3) & 1;
    int wgp = (gsel ? 32 : 0) + 4 * nh + j;
    widx = (lane < 16) ? (wgp * 8 + khp * 4 + rtb) : myf;   // own flag = benign (set below)
  }
  // h fragment stream base (within one parity buffer):
  const size_t hoff = (((size_t)kh * 64 + rt) * 64 + lane) * 16;
  const char* hbase0 = (const char*)hfrag;                          // parity 0
  const char* hbase1 = (const char*)hfrag + (size_t)BB * HH * 2;    // parity 1
  unsigned* hw32 = (unsigned*)hfrag;
  const size_t hui = ((((size_t)(d0 >> 5) * 4 + (b >> 4)) * 64
                      + ((b & 15) + (((d0 >> 3) & 3) << 4))) * 4 + ((d0 & 7) >> 1));
  const char* fp  = (const char*)fgbuf + (((size_t)b * H2) + d0) * 4;
  const char* gp  = fp + (size_t)HH * 4;

  for (int t = 0; t < TT; ++t) {
    const int e = epoch0 + t + 1;
    const size_t row = (size_t)t * BB + b;
    // ---- prefetch phase-B inputs (cached; consumed after fg wait) ----
    const f16* xr = x2fg + row * H2;
    f16x2 xf = *(const f16x2*)&xr[d0];
    f16x2 xg = *(const f16x2*)&xr[HH + d0];
    int   p  = inv[row];

    // ---- wait: h(t-1) for THIS K-half: 256 producer-wave flags (wgs [32kh,+32)) ----
    for (;;) {
      int ok = 1;
#pragma unroll
      for (int j = 0; j < 4; ++j) {
        int v = ALOAD32(&Bfl[256 * kh + j * 64 + lane]);
        ok &= (v >= e - 1);
      }
      if (__all(ok)) break;
      __builtin_amdgcn_s_sleep(1);
    }

    // ---------- phase A: K-half partials for both ct tiles ----------
    f32x4 acc0 = {0.f, 0.f, 0.f, 0.f}, acc1 = acc0;
    {
      const char* hb0 = ((t & 1) ? hbase0 : hbase1) + hoff;   // read parity (t+1)&1
      float4 hb[16];
#pragma unroll
      for (int j = 0; j < 16; ++j) {
        asm volatile("global_load_dwordx4 %0, %1, off sc0 sc1"
                     : "=v"(hb[j]) : "v"(hb0 + (size_t)j * 4096));
      }
      asm volatile("s_waitcnt vmcnt(0)" ::: "memory");
      __builtin_amdgcn_sched_barrier(0);
#pragma unroll
      for (int j = 0; j < 16; ++j) {
        int kk = kh * 16 + j;
        f16x8 af = __builtin_bit_cast(f16x8, hb[j]);
        f16x8 b0 = *(const f16x8*)&Wlds[((kk * 2 + 0) * 64 + lane) * 8];
        f16x8 b1 = *(const f16x8*)&Wlds[((kk * 2 + 1) * 64 + lane) * 8];
        acc0 = __builtin_amdgcn_mfma_f32_16x16x32_f16(af, b0, acc0, 0, 0, 0);
        acc1 = __builtin_amdgcn_mfma_f32_16x16x32_f16(af, b1, acc1, 0, 0, 0);
      }
    }
    // half-K reduction via parity pbuf; the SOLE per-step rendezvous.
    pbuf[t & 1][wave][lane] = (kh == 0) ? acc1 : acc0;
    __syncthreads();
    {
      f32x4 acc = ((kh == 0) ? acc0 : acc1) + pbuf[t & 1][wave ^ 4][lane];
      const int col = cs * 32 + kh * 16 + (lane & 15);
      const int r0  = rt * 16 + (lane >> 4) * 4;
#pragma unroll
      for (int r = 0; r < 4; ++r) ASTORE(&fgbuf[(size_t)(r0 + r) * H2 + col], acc[r]);
    }
    // per-wave drain + flag (no rendezvous)
    asm volatile("s_waitcnt vmcnt(0)" ::: "memory");
    __builtin_amdgcn_sched_barrier(0);
    if (lane == 0) ASTORE(&Afl[myf], e);

    // ---- wait: 16 exact fg-producer waves ----
    for (;;) {
      int v = ALOAD32(&Afl[widx]);
      if (__all(v >= e)) break;
      __builtin_amdgcn_s_sleep(1);
    }

    // ---------- phase B ----------
    float2 fv, gv;
    asm volatile("global_load_dwordx2 %0, %1, off sc0 sc1" : "=v"(fv) : "v"(fp));
    asm volatile("global_load_dwordx2 %0, %1, off sc0 sc1" : "=v"(gv) : "v"(gp));
    asm volatile("s_waitcnt vmcnt(0)" ::: "memory");
    __builtin_amdgcn_sched_barrier(0);
    float f0 = fv.x + bf2.x + (float)xf.x;
    float f1 = fv.y + bf2.y + (float)xf.y;
    float g0 = gv.x + bg2.x + (float)xg.x;
    float g1 = gv.y + bg2.y + (float)xg.y;
    *(float2*)&fbuf[wave][2 * lane] = make_float2(f0, f1);
    float s = 0.f;
#pragma unroll
    for (int i = 0; i < 32; ++i) {
      float4 fvv = *(const float4*)&fbuf[wave][4 * i];
      f16x4 rv = Rq[i * 64 + lane];
      s = fmaf(fvv.x, (float)rv.x, s);
      s = fmaf(fvv.y, (float)rv.y, s);
      s = fmaf(fvv.z, (float)rv.z, s);
      s = fmaf(fvv.w, (float)rv.w, s);
    }
    float mx = s;
#pragma unroll
    for (int off = 32; off > 0; off >>= 1) mx = fmaxf(mx, __shfl_xor(mx, off));
    float e2 = expf(s - mx);
    float sum = e2;
#pragma unroll
    for (int off = 32; off > 0; off >>= 1) sum += __shfl_xor(sum, off);
    abuf[wave][lane] = e2 / sum;
    float bd0 = 0.f, bd1 = 0.f;
#pragma unroll
    for (int i = 0; i < 16; ++i) {
      float4 av = *(const float4*)&abuf[wave][4 * i];
      f16x4 u01 = Uq[(i * 2 + 0) * 64 + lane];
      f16x4 u23 = Uq[(i * 2 + 1) * 64 + lane];
      bd0 = fmaf(av.x, (float)u01.x, bd0); bd1 = fmaf(av.x, (float)u01.y, bd1);
      bd0 = fmaf(av.y, (float)u01.z, bd0); bd1 = fmaf(av.y, (float)u01.w, bd1);
      bd0 = fmaf(av.z, (float)u23.x, bd0); bd1 = fmaf(av.z, (float)u23.y, bd1);
      bd0 = fmaf(av.w, (float)u23.z, bd0); bd1 = fmaf(av.w, (float)u23.w, bd1);
    }
    float gt0 = 1.f / (1.f + expf(-g0));
    float gt1 = 1.f / (1.f + expf(-g1));
    float hv0 = gt0 * tanhf(bd0) + (1.f - gt0) * ho0;
    float hv1 = gt1 * tanhf(bd1) + (1.f - gt1) * ho1;
    ho0 = hv0; ho1 = hv1;
    {
      unsigned hp = (unsigned)__builtin_bit_cast(unsigned short, (f16)hv0)
                  | ((unsigned)__builtin_bit_cast(unsigned short, (f16)hv1) << 16);
      ASTORE(hw32 + (size_t)(t & 1) * (BB * HH / 2) + hui, hp);   // parity t&1
    }
    // per-wave drain + flag (no rendezvous)
    asm volatile("s_waitcnt vmcnt(0)" ::: "memory");
    __builtin_amdgcn_sched_barrier(0);
    if (lane == 0) ASTORE(&Bfl[myf], e);

    // ---- deferred output writes: overlap with other wgs' polling ----
    if (hs_out) {
      f16x2 hp2; hp2.x = (f16)ho0; hp2.y = (f16)ho1;
      *(f16x2*)&hs_out[row * HH + d0] = hp2;
    }
    if (out_packed && p >= 0) {
      *(float2*)&out_packed[(size_t)p * HH + d0] = make_float2(ho0, ho1);
    }
    if (lb == t + 1) {
      *(float2*)&hn_out[(size_t)b * HH + d0] = make_float2(ho0, ho1);
    }
  }
}

// ---------------- host ----------------
extern "C" void kernel_launch(void* const* d_in, const int* in_sizes, int n_in,
                              void* d_out, int out_size, void* d_ws, size_t ws_size,
                              hipStream_t stream) {
  const float* x      = (const float*)d_in[0];
  const int*   idx    = (const int*)d_in[1];
  const int*   lgt    = (const int*)d_in[2];
  const float* basis0 = (const float*)d_in[3];
  const float* basis1 = (const float*)d_in[4];
  const float* Wx0 = (const float*)d_in[5];  const float* bx0 = (const float*)d_in[6];
  const float* Wh0 = (const float*)d_in[7];  const float* bh0 = (const float*)d_in[8];
  const float* Wv0 = (const float*)d_in[9];  const float* bv0 = (const float*)d_in[10];
  const float* Wx1 = (const float*)d_in[11]; const float* bx1 = (const float*)d_in[12];
  const float* Wh1 = (const float*)d_in[13]; const float* bh1 = (const float*)d_in[14];
  const float* Wv1 = (const float*)d_in[15]; const float* bv1 = (const float*)d_in[16];
  const int total = in_sizes[1];

  char* ws = (char*)d_ws;
  size_t off = 0;
  auto alloc = [&](size_t bytes) -> void* {
    void* p = (void*)(ws + off);
    off += (bytes + 255) & ~(size_t)255;
    return p;
  };

  int*   Afl     = (int*)alloc(RWG * 8 * 4);               // per-wave flags
  int*   Bfl     = (int*)alloc(RWG * 8 * 4);
  int*   inv     = (int*)alloc((size_t)MROWS * 4);
  f16*   xpad    = (f16*)alloc((size_t)MROWS * DD * 2);
  f16*   x2fg    = (f16*)alloc((size_t)MROWS * H2 * 2);
  f16*   hfrag   = (f16*)alloc((size_t)2 * BB * HH * 2);   // parity double-buffer
  float* fgbuf   = (float*)alloc((size_t)BB * H2 * 4);
  f16* Wx0h = (f16*)alloc((size_t)H2 * DD * 2);
  f16* Wh0h = (f16*)alloc((size_t)H2 * HH * 2);
  f16* Wv0h = (f16*)alloc((size_t)H2 * HH * 2);
  f16* Wx1h = (f16*)alloc((size_t)H2 * HH * 2);
  f16* Wh1h = (f16*)alloc((size_t)H2 * HH * 2);
  f16* Wv1h = (f16*)alloc((size_t)H2 * HH * 2);
  f16* bas0h = (f16*)alloc((size_t)128 * HH * 2);
  f16* bas1h = (f16*)alloc((size_t)128 * HH * 2);
  f16* v0h = (f16*)alloc((size_t)NR_ * H2 * 2);
  f16* v1h = (f16*)alloc((size_t)NR_ * H2 * 2);

  float* out = (float*)d_out;
  float* hn0 = out + (size_t)total * HH;
  float* hn1 = hn0 + (size_t)BB * HH;
  f16* hs0 = (f16*)d_out;   // layer-0 hidden stash (64 MB), dead before layer-1 output

  (void)hipMemsetAsync(Afl, 0, RWG * 8 * 4, stream);
  (void)hipMemsetAsync(Bfl, 0, RWG * 8 * 4, stream);
  (void)hipMemsetAsync(inv, 0xFF, (size_t)MROWS * 4, stream);
  (void)hipMemsetAsync(xpad, 0, (size_t)MROWS * DD * 2, stream);
  (void)hipMemsetAsync(bas0h, 0, (size_t)128 * HH * 2, stream);
  (void)hipMemsetAsync(bas1h, 0, (size_t)128 * HH * 2, stream);
  (void)hipMemsetAsync(hfrag, 0, (size_t)2 * BB * HH * 2, stream);

  k_cvt<<<512, 256, 0, stream>>>(Wx0, Wx0h, H2 * DD);
  k_cvt<<<512, 256, 0, stream>>>(Wh0, Wh0h, H2 * HH);
  k_cvt<<<512, 256, 0, stream>>>(Wv0, Wv0h, H2 * HH);
  k_cvt<<<512, 256, 0, stream>>>(Wx1, Wx1h, H2 * HH);
  k_cvt<<<512, 256, 0, stream>>>(Wh1, Wh1h, H2 * HH);
  k_cvt<<<512, 256, 0, stream>>>(Wv1, Wv1h, H2 * HH);
  k_cvt<<<64, 256, 0, stream>>>(basis0, bas0h, NR_ * HH);
  k_cvt<<<64, 256, 0, stream>>>(basis1, bas1h, NR_ * HH);
  k_scatter<<<2048, 256, 0, stream>>>(x, idx, xpad, total);
  k_inv<<<(total + 255) / 256, 256, 0, stream>>>(idx, inv, total);

  dim3 gv(16, 1);
  k_gemm<<<gv, 256, 0, stream>>>(bas0h, Wv0h, bv0, v0h, H2, HH, NR_);
  k_gemm<<<gv, 256, 0, stream>>>(bas1h, Wv1h, bv1, v1h, H2, HH, NR_);

  dim3 gx(H2 / 128, MROWS / 128);
  k_gemm<<<gx, 256, 0, stream>>>(xpad, Wx0h, bx0, x2fg, H2, DD, MROWS);

  k_rec<<<RWG, 512, 0, stream>>>(Wh0h, bh0, v0h, x2fg, hfrag, fgbuf,
                                 hs0, nullptr, hn0, inv, lgt, Afl, Bfl, 0);

  (void)hipMemsetAsync(hfrag, 0, (size_t)2 * BB * HH * 2, stream);

  k_gemm<<<gx, 256, 0, stream>>>(hs0, Wx1h, bx1, x2fg, H2, HH, MROWS);

  k_rec<<<RWG, 512, 0, stream>>>(Wh1h, bh1, v1h, x2fg, hfrag, fgbuf,
                                 nullptr, out, hn1, inv, lgt, Afl, Bfl, TT);
}

// Round 15
// 9870.104 us; speedup vs baseline: 1.4658x; 1.4658x over previous
//
#include <hip/hip_runtime.h>

typedef _Float16 f16;
typedef _Float16 f16x2 __attribute__((ext_vector_type(2)));
typedef _Float16 f16x4 __attribute__((ext_vector_type(4)));
typedef _Float16 f16x8 __attribute__((ext_vector_type(8)));
typedef float    f32x4 __attribute__((ext_vector_type(4)));

#define TT   512
#define BB   64
#define DD   512
#define HH   1024
#define H2   2048
#define NR_  64
#define NH_  8
#define HD_  128
#define MROWS (TT*BB)      // 32768
#define RWG  64            // recurrence workgroups

#define ALOAD32(p)   __hip_atomic_load((p),  __ATOMIC_RELAXED, __HIP_MEMORY_SCOPE_AGENT)
#define ASTORE(p,v)  __hip_atomic_store((p), (v), __ATOMIC_RELAXED, __HIP_MEMORY_SCOPE_AGENT)

// ---------------- prep kernels ----------------
__global__ void k_cvt(const float* __restrict__ s, f16* __restrict__ d, int n) {
  int i = blockIdx.x * blockDim.x + threadIdx.x;
  int st = gridDim.x * blockDim.x;
  for (; i < n; i += st) d[i] = (f16)s[i];
}

__global__ void k_scatter(const float* __restrict__ x, const int* __restrict__ idx,
                          f16* __restrict__ xpad, int total) {
  int i = blockIdx.x * blockDim.x + threadIdx.x;
  int st = gridDim.x * blockDim.x;
  int n = total * DD;
  for (; i < n; i += st) {
    int p = i >> 9;          // / DD
    int j = i & (DD - 1);
    xpad[(size_t)idx[p] * DD + j] = (f16)x[i];
  }
}

__global__ void k_inv(const int* __restrict__ idx, int* __restrict__ inv, int total) {
  int i = blockIdx.x * blockDim.x + threadIdx.x;
  if (i < total) inv[idx[i]] = i;
}

// ---------------- fp16 GEMM: C[m,n] = sum_k A[m,k]*Bw[n,k] + bias[n] ----------------
__global__ __launch_bounds__(256)
void k_gemm(const f16* __restrict__ A, const f16* __restrict__ Bw,
            const float* __restrict__ bias, f16* __restrict__ C,
            int N, int K, int Mvalid) {
  __shared__ __align__(16) f16 As[128 * 32];
  __shared__ __align__(16) f16 Bs[128 * 32];
  const int tid  = threadIdx.x;
  const int lane = tid & 63;
  const int wave = tid >> 6;
  const int m0 = blockIdx.y * 128;
  const int n0 = blockIdx.x * 128;
  const int mw = (wave >> 1) * 64;
  const int nw = (wave & 1) * 64;
  const int NT = K >> 5;
  const int c0 = tid * 2;

  float4 pa[2], pb[2];
  auto fetch = [&](int kt) {
#pragma unroll
    for (int i = 0; i < 2; ++i) {
      int c = c0 + i;
      int row = c >> 2, kc = c & 3;
      pa[i] = *(const float4*)&A [(size_t)(m0 + row) * K + kt * 32 + kc * 8];
      pb[i] = *(const float4*)&Bw[(size_t)(n0 + row) * K + kt * 32 + kc * 8];
    }
  };

  f32x4 acc[4][4] = {};
  fetch(0);
  for (int kt = 0; kt < NT; ++kt) {
    __syncthreads();
#pragma unroll
    for (int i = 0; i < 2; ++i) {
      int c = c0 + i;
      *(float4*)&As[c * 8] = pa[i];
      *(float4*)&Bs[c * 8] = pb[i];
    }
    __syncthreads();
    if (kt + 1 < NT) fetch(kt + 1);
    f16x8 af[4], bf[4];
#pragma unroll
    for (int i = 0; i < 4; ++i) {
      af[i] = *(const f16x8*)&As[(mw + i * 16 + (lane & 15)) * 32 + (lane >> 4) * 8];
      bf[i] = *(const f16x8*)&Bs[(nw + i * 16 + (lane & 15)) * 32 + (lane >> 4) * 8];
    }
#pragma unroll
    for (int i = 0; i < 4; ++i)
#pragma unroll
      for (int j = 0; j < 4; ++j)
        acc[i][j] = __builtin_amdgcn_mfma_f32_16x16x32_f16(af[i], bf[j], acc[i][j], 0, 0, 0);
  }

#pragma unroll
  for (int j = 0; j < 4; ++j) {
    int col = n0 + nw + j * 16 + (lane & 15);
    float bv = bias[col];
#pragma unroll
    for (int i = 0; i < 4; ++i) {
#pragma unroll
      for (int r = 0; r < 4; ++r) {
        int row = m0 + mw + i * 16 + (lane >> 4) * 4 + r;
        if (row < Mvalid) C[(size_t)row * N + col] = (f16)(acc[i][j][r] + bv);
      }
    }
  }
}

// ---------------- persistent recurrence kernel (dataflow flags, no global barrier) ----
// r11 structure (PASSED, 4.51 ms/dispatch) with ONE refinement: the phase-A h-wait
// is narrowed from all 64 wgs to the 32 wgs that produce this wave's K-half
// (dims [kh*512,+512) <- heads 4kh..4kh+3 <- wgs [32kh,32kh+32)). Same poll
// traffic (1 dword/lane/spin), strictly weaker predicate: the early half starts
// its h-load+MFMA while the late half's producers finish. The pbuf __syncthreads
// still joins BOTH halves before any fg store, so fg stores remain gated on all
// 64 Bfl >= t-1 — the single-buffer fgbuf and h-parity safety proofs of r11 are
// unchanged.
__global__ __launch_bounds__(512, 2)
void k_rec(const f16* __restrict__ Wh16, const float* __restrict__ bh,
           const f16* __restrict__ v16,  const f16* __restrict__ x2fg,
           f16* __restrict__ hfrag, float* __restrict__ fgbuf,
           f16* __restrict__ hs_out, float* __restrict__ out_packed,
           float* __restrict__ hn_out,
           const int* __restrict__ inv, const int* __restrict__ lgt,
           int* __restrict__ Afl, int* __restrict__ Bfl, int epoch0)
{
  __shared__ __align__(16) f16   Wlds[32 * 2 * 64 * 8];  // 64 KB [kk][ct][lane][8]
  __shared__ __align__(16) f16x4 Rq[32 * 64];            // 16 KB
  __shared__ __align__(16) f16x4 Uq[16 * 2 * 64];        // 16 KB
  __shared__ __align__(16) f32x4 pbuf[8][64];            // 8 KB: half-K partial tiles
  __shared__ __align__(16) float fbuf[8][128];           // 4 KB (wave-private rows)
  __shared__ __align__(16) float abuf[8][64];            // 2 KB (wave-private rows)

  const int tid  = threadIdx.x;
  const int lane = tid & 63;
  const int wave = tid >> 6;
  const int wg   = blockIdx.x;
  const int cs   = wg;                   // col-slice: cols cs*32 .. cs*32+32
  const int rt   = wave & 3;             // row tile 0..3
  const int kh   = wave >> 2;            // K-half 0/1
  const int nh   = wg >> 3;
  const int b    = ((wg & 7) << 3) + wave;
  const int cf   = nh * HD_;

  // stage full-K Wh slice (32 cols) into LDS in MFMA B-fragment layout
  for (int i = tid; i < 32 * 2 * 64; i += 512) {
    int kk = i >> 7;
    int nt = (i >> 6) & 1;
    int ln = i & 63;
    int col = cs * 32 + nt * 16 + (ln & 15);
    int kg  = kk * 32 + (ln >> 4) * 8;
    *(float4*)&Wlds[(size_t)i * 8] = *(const float4*)&Wh16[(size_t)col * HH + kg];
  }
  // role basis -> LDS
  for (int e = tid; e < 32 * 64; e += 512) {
    int i = e >> 6, role = e & 63;
    Rq[e] = *(const f16x4*)&v16[(size_t)role * H2 + nh * 256 + 4 * i];
  }
  // unbind basis -> LDS
  for (int e = tid; e < 16 * 2 * 64; e += 512) {
    int i = e >> 7, half = (e >> 6) & 1, l = e & 63;
    int r0 = 4 * i + 2 * half;
    const f16* u0 = &v16[(size_t)r0 * H2 + nh * 256 + 128 + 2 * l];
    const f16* u1 = &v16[(size_t)(r0 + 1) * H2 + nh * 256 + 128 + 2 * l];
    f16x4 tv; tv.x = u0[0]; tv.y = u0[1]; tv.z = u1[0]; tv.w = u1[1];
    Uq[e] = tv;
  }
  __syncthreads();

  const int d0 = cf + 2 * lane;
  const float2 bf2 = *(const float2*)&bh[d0];
  const float2 bg2 = *(const float2*)&bh[HH + d0];
  const int lb = lgt[b];
  float ho0 = 0.f, ho1 = 0.f;
  // fg producer flags for head nh: f = slices 4nh..4nh+3, g = slices 32+4nh..+3
  const int pidx = (lane < 4) ? (4 * nh + lane)
                 : (lane < 8) ? (28 + 4 * nh + lane)   // 32 + 4nh + (lane-4)
                 : wg;                                 // benign dummy
  // this wave's h-producer flag index: wgs [32kh, 32kh+32), each lane covers one
  const int hidx = 32 * kh + (lane & 31);
  // h fragment stream base (within one parity buffer):
  const size_t hoff = (((size_t)kh * 64 + rt) * 64 + lane) * 16;
  const char* hbase0 = (const char*)hfrag;                          // parity 0
  const char* hbase1 = (const char*)hfrag + (size_t)BB * HH * 2;    // parity 1
  unsigned* hw32 = (unsigned*)hfrag;
  const size_t hui = ((((size_t)(d0 >> 5) * 4 + (b >> 4)) * 64
                      + ((b & 15) + (((d0 >> 3) & 3) << 4))) * 4 + ((d0 & 7) >> 1));
  const char* fp  = (const char*)fgbuf + (((size_t)b * H2) + d0) * 4;
  const char* gp  = fp + (size_t)HH * 4;

  for (int t = 0; t < TT; ++t) {
    const int e = epoch0 + t + 1;
    const size_t row = (size_t)t * BB + b;
    // ---- prefetch phase-B inputs (cached; consumed after fg wait) ----
    const f16* xr = x2fg + row * H2;
    f16x2 xf = *(const f16x2*)&xr[d0];
    f16x2 xg = *(const f16x2*)&xr[HH + d0];
    int   p  = inv[row];

    // ---- wait: h(t-1) for THIS K-half only (32 producer wgs) ----
    for (;;) {
      int v = ALOAD32(&Bfl[hidx]);
      if (__all(v >= e - 1)) break;
      __builtin_amdgcn_s_sleep(1);
    }

    // ---------- phase A: K-half partials for both ct tiles ----------
    f32x4 acc0 = {0.f, 0.f, 0.f, 0.f}, acc1 = acc0;
    {
      const char* hb0 = ((t & 1) ? hbase0 : hbase1) + hoff;   // read parity (t+1)&1
      float4 hb[16];
#pragma unroll
      for (int j = 0; j < 16; ++j) {
        asm volatile("global_load_dwordx4 %0, %1, off sc0 sc1"
                     : "=v"(hb[j]) : "v"(hb0 + (size_t)j * 4096));
      }
      asm volatile("s_waitcnt vmcnt(0)" ::: "memory");
      __builtin_amdgcn_sched_barrier(0);
#pragma unroll
      for (int j = 0; j < 16; ++j) {
        int kk = kh * 16 + j;
        f16x8 af = __builtin_bit_cast(f16x8, hb[j]);
        f16x8 b0 = *(const f16x8*)&Wlds[((kk * 2 + 0) * 64 + lane) * 8];
        f16x8 b1 = *(const f16x8*)&Wlds[((kk * 2 + 1) * 64 + lane) * 8];
        acc0 = __builtin_amdgcn_mfma_f32_16x16x32_f16(af, b0, acc0, 0, 0, 0);
        acc1 = __builtin_amdgcn_mfma_f32_16x16x32_f16(af, b1, acc1, 0, 0, 0);
      }
    }
    // half-K reduction: wave (rt,kh) finalizes ct==kh; stores the other partial.
    // This rendezvous joins BOTH halves => fg stores below are all-64 gated.
    pbuf[wave][lane] = (kh == 0) ? acc1 : acc0;
    __syncthreads();
    {
      f32x4 acc = ((kh == 0) ? acc0 : acc1) + pbuf[wave ^ 4][lane];
      const int col = cs * 32 + kh * 16 + (lane & 15);
      const int r0  = rt * 16 + (lane >> 4) * 4;
#pragma unroll
      for (int r = 0; r < 4; ++r) ASTORE(&fgbuf[(size_t)(r0 + r) * H2 + col], acc[r]);
    }
    __syncthreads();                 // drain all waves' fg stores (vmcnt0 before barrier)
    if (tid == 0) ASTORE(&Afl[wg], e);

    // ---- wait: this head's 8 fg producers done ----
    for (;;) {
      int v = ALOAD32(&Afl[pidx]);
      if (__all((lane >= 8) | (v >= e))) break;
      __builtin_amdgcn_s_sleep(1);
    }

    // ---------- phase B ----------
    float2 fv, gv;
    asm volatile("global_load_dwordx2 %0, %1, off sc0 sc1" : "=v"(fv) : "v"(fp));
    asm volatile("global_load_dwordx2 %0, %1, off sc0 sc1" : "=v"(gv) : "v"(gp));
    asm volatile("s_waitcnt vmcnt(0)" ::: "memory");
    __builtin_amdgcn_sched_barrier(0);
    float f0 = fv.x + bf2.x + (float)xf.x;
    float f1 = fv.y + bf2.y + (float)xf.y;
    float g0 = gv.x + bg2.x + (float)xg.x;
    float g1 = gv.y + bg2.y + (float)xg.y;
    *(float2*)&fbuf[wave][2 * lane] = make_float2(f0, f1);
    float s = 0.f;
#pragma unroll
    for (int i = 0; i < 32; ++i) {
      float4 fvv = *(const float4*)&fbuf[wave][4 * i];
      f16x4 rv = Rq[i * 64 + lane];
      s = fmaf(fvv.x, (float)rv.x, s);
      s = fmaf(fvv.y, (float)rv.y, s);
      s = fmaf(fvv.z, (float)rv.z, s);
      s = fmaf(fvv.w, (float)rv.w, s);
    }
    float mx = s;
#pragma unroll
    for (int off = 32; off > 0; off >>= 1) mx = fmaxf(mx, __shfl_xor(mx, off));
    float e2 = expf(s - mx);
    float sum = e2;
#pragma unroll
    for (int off = 32; off > 0; off >>= 1) sum += __shfl_xor(sum, off);
    abuf[wave][lane] = e2 / sum;
    float bd0 = 0.f, bd1 = 0.f;
#pragma unroll
    for (int i = 0; i < 16; ++i) {
      float4 av = *(const float4*)&abuf[wave][4 * i];
      f16x4 u01 = Uq[(i * 2 + 0) * 64 + lane];
      f16x4 u23 = Uq[(i * 2 + 1) * 64 + lane];
      bd0 = fmaf(av.x, (float)u01.x, bd0); bd1 = fmaf(av.x, (float)u01.y, bd1);
      bd0 = fmaf(av.y, (float)u01.z, bd0); bd1 = fmaf(av.y, (float)u01.w, bd1);
      bd0 = fmaf(av.z, (float)u23.x, bd0); bd1 = fmaf(av.z, (float)u23.y, bd1);
      bd0 = fmaf(av.w, (float)u23.z, bd0); bd1 = fmaf(av.w, (float)u23.w, bd1);
    }
    float gt0 = 1.f / (1.f + expf(-g0));
    float gt1 = 1.f / (1.f + expf(-g1));
    float hv0 = gt0 * tanhf(bd0) + (1.f - gt0) * ho0;
    float hv1 = gt1 * tanhf(bd1) + (1.f - gt1) * ho1;
    ho0 = hv0; ho1 = hv1;
    {
      unsigned hp = (unsigned)__builtin_bit_cast(unsigned short, (f16)hv0)
                  | ((unsigned)__builtin_bit_cast(unsigned short, (f16)hv1) << 16);
      ASTORE(hw32 + (size_t)(t & 1) * (BB * HH / 2) + hui, hp);   // parity t&1
    }
    __syncthreads();                 // drain all waves' h stores
    if (tid == 0) ASTORE(&Bfl[wg], e);

    // ---- deferred output writes: overlap with other wgs' polling ----
    if (hs_out) {
      f16x2 hp2; hp2.x = (f16)ho0; hp2.y = (f16)ho1;
      *(f16x2*)&hs_out[row * HH + d0] = hp2;
    }
    if (out_packed && p >= 0) {
      *(float2*)&out_packed[(size_t)p * HH + d0] = make_float2(ho0, ho1);
    }
    if (lb == t + 1) {
      *(float2*)&hn_out[(size_t)b * HH + d0] = make_float2(ho0, ho1);
    }
  }
}

// ---------------- host ----------------
extern "C" void kernel_launch(void* const* d_in, const int* in_sizes, int n_in,
                              void* d_out, int out_size, void* d_ws, size_t ws_size,
                              hipStream_t stream) {
  const float* x      = (const float*)d_in[0];
  const int*   idx    = (const int*)d_in[1];
  const int*   lgt    = (const int*)d_in[2];
  const float* basis0 = (const float*)d_in[3];
  const float* basis1 = (const float*)d_in[4];
  const float* Wx0 = (const float*)d_in[5];  const float* bx0 = (const float*)d_in[6];
  const float* Wh0 = (const float*)d_in[7];  const float* bh0 = (const float*)d_in[8];
  const float* Wv0 = (const float*)d_in[9];  const float* bv0 = (const float*)d_in[10];
  const float* Wx1 = (const float*)d_in[11]; const float* bx1 = (const float*)d_in[12];
  const float* Wh1 = (const float*)d_in[13]; const float* bh1 = (const float*)d_in[14];
  const float* Wv1 = (const float*)d_in[15]; const float* bv1 = (const float*)d_in[16];
  const int total = in_sizes[1];

  char* ws = (char*)d_ws;
  size_t off = 0;
  auto alloc = [&](size_t bytes) -> void* {
    void* p = (void*)(ws + off);
    off += (bytes + 255) & ~(size_t)255;
    return p;
  };

  int*   Afl     = (int*)alloc(RWG * 4);
  int*   Bfl     = (int*)alloc(RWG * 4);
  int*   inv     = (int*)alloc((size_t)MROWS * 4);
  f16*   xpad    = (f16*)alloc((size_t)MROWS * DD * 2);
  f16*   x2fg    = (f16*)alloc((size_t)MROWS * H2 * 2);
  f16*   hfrag   = (f16*)alloc((size_t)2 * BB * HH * 2);   // parity double-buffer
  float* fgbuf   = (float*)alloc((size_t)BB * H2 * 4);
  f16* Wx0h = (f16*)alloc((size_t)H2 * DD * 2);
  f16* Wh0h = (f16*)alloc((size_t)H2 * HH * 2);
  f16* Wv0h = (f16*)alloc((size_t)H2 * HH * 2);
  f16* Wx1h = (f16*)alloc((size_t)H2 * HH * 2);
  f16* Wh1h = (f16*)alloc((size_t)H2 * HH * 2);
  f16* Wv1h = (f16*)alloc((size_t)H2 * HH * 2);
  f16* bas0h = (f16*)alloc((size_t)128 * HH * 2);
  f16* bas1h = (f16*)alloc((size_t)128 * HH * 2);
  f16* v0h = (f16*)alloc((size_t)NR_ * H2 * 2);
  f16* v1h = (f16*)alloc((size_t)NR_ * H2 * 2);

  float* out = (float*)d_out;
  float* hn0 = out + (size_t)total * HH;
  float* hn1 = hn0 + (size_t)BB * HH;
  f16* hs0 = (f16*)d_out;   // layer-0 hidden stash (64 MB), dead before layer-1 output

  (void)hipMemsetAsync(Afl, 0, RWG * 4, stream);
  (void)hipMemsetAsync(Bfl, 0, RWG * 4, stream);
  (void)hipMemsetAsync(inv, 0xFF, (size_t)MROWS * 4, stream);
  (void)hipMemsetAsync(xpad, 0, (size_t)MROWS * DD * 2, stream);
  (void)hipMemsetAsync(bas0h, 0, (size_t)128 * HH * 2, stream);
  (void)hipMemsetAsync(bas1h, 0, (size_t)128 * HH * 2, stream);
  (void)hipMemsetAsync(hfrag, 0, (size_t)2 * BB * HH * 2, stream);

  k_cvt<<<512, 256, 0, stream>>>(Wx0, Wx0h, H2 * DD);
  k_cvt<<<512, 256, 0, stream>>>(Wh0, Wh0h, H2 * HH);
  k_cvt<<<512, 256, 0, stream>>>(Wv0, Wv0h, H2 * HH);
  k_cvt<<<512, 256, 0, stream>>>(Wx1, Wx1h, H2 * HH);
  k_cvt<<<512, 256, 0, stream>>>(Wh1, Wh1h, H2 * HH);
  k_cvt<<<512, 256, 0, stream>>>(Wv1, Wv1h, H2 * HH);
  k_cvt<<<64, 256, 0, stream>>>(basis0, bas0h, NR_ * HH);
  k_cvt<<<64, 256, 0, stream>>>(basis1, bas1h, NR_ * HH);
  k_scatter<<<2048, 256, 0, stream>>>(x, idx, xpad, total);
  k_inv<<<(total + 255) / 256, 256, 0, stream>>>(idx, inv, total);

  dim3 gv(16, 1);
  k_gemm<<<gv, 256, 0, stream>>>(bas0h, Wv0h, bv0, v0h, H2, HH, NR_);
  k_gemm<<<gv, 256, 0, stream>>>(bas1h, Wv1h, bv1, v1h, H2, HH, NR_);

  dim3 gx(H2 / 128, MROWS / 128);
  k_gemm<<<gx, 256, 0, stream>>>(xpad, Wx0h, bx0, x2fg, H2, DD, MROWS);

  k_rec<<<RWG, 512, 0, stream>>>(Wh0h, bh0, v0h, x2fg, hfrag, fgbuf,
                                 hs0, nullptr, hn0, inv, lgt, Afl, Bfl, 0);

  (void)hipMemsetAsync(hfrag, 0, (size_t)2 * BB * HH * 2, stream);

  k_gemm<<<gx, 256, 0, stream>>>(hs0, Wx1h, bx1, x2fg, H2, HH, MROWS);

  k_rec<<<RWG, 512, 0, stream>>>(Wh1h, bh1, v1h, x2fg, hfrag, fgbuf,
                                 nullptr, out, hn1, inv, lgt, Afl, Bfl, TT);
}

// Round 17
// 9752.986 us; speedup vs baseline: 1.4834x; 1.0120x over previous
//
#include <hip/hip_runtime.h>

typedef _Float16 f16;
typedef _Float16 f16x2 __attribute__((ext_vector_type(2)));
typedef _Float16 f16x4 __attribute__((ext_vector_type(4)));
typedef _Float16 f16x8 __attribute__((ext_vector_type(8)));
typedef float    f32x4 __attribute__((ext_vector_type(4)));

#define TT   512
#define BB   64
#define DD   512
#define HH   1024
#define H2   2048
#define NR_  64
#define NH_  8
#define HD_  128
#define MROWS (TT*BB)      // 32768
#define RWG  64            // recurrence workgroups

#define ALOAD32(p)   __hip_atomic_load((p),  __ATOMIC_RELAXED, __HIP_MEMORY_SCOPE_AGENT)
#define ASTORE(p,v)  __hip_atomic_store((p), (v), __ATOMIC_RELAXED, __HIP_MEMORY_SCOPE_AGENT)

// ---------------- prep kernels ----------------
__global__ void k_cvt(const float* __restrict__ s, f16* __restrict__ d, int n) {
  int i = blockIdx.x * blockDim.x + threadIdx.x;
  int st = gridDim.x * blockDim.x;
  for (; i < n; i += st) d[i] = (f16)s[i];
}

__global__ void k_scatter(const float* __restrict__ x, const int* __restrict__ idx,
                          f16* __restrict__ xpad, int total) {
  int i = blockIdx.x * blockDim.x + threadIdx.x;
  int st = gridDim.x * blockDim.x;
  int n = total * DD;
  for (; i < n; i += st) {
    int p = i >> 9;          // / DD
    int j = i & (DD - 1);
    xpad[(size_t)idx[p] * DD + j] = (f16)x[i];
  }
}

__global__ void k_inv(const int* __restrict__ idx, int* __restrict__ inv, int total) {
  int i = blockIdx.x * blockDim.x + threadIdx.x;
  if (i < total) inv[idx[i]] = i;
}

// ---------------- fp16 GEMM: C[m,n] = sum_k A[m,k]*Bw[n,k] + bias[n] ----------------
__global__ __launch_bounds__(256)
void k_gemm(const f16* __restrict__ A, const f16* __restrict__ Bw,
            const float* __restrict__ bias, f16* __restrict__ C,
            int N, int K, int Mvalid) {
  __shared__ __align__(16) f16 As[128 * 32];
  __shared__ __align__(16) f16 Bs[128 * 32];
  const int tid  = threadIdx.x;
  const int lane = tid & 63;
  const int wave = tid >> 6;
  const int m0 = blockIdx.y * 128;
  const int n0 = blockIdx.x * 128;
  const int mw = (wave >> 1) * 64;
  const int nw = (wave & 1) * 64;
  const int NT = K >> 5;
  const int c0 = tid * 2;

  float4 pa[2], pb[2];
  auto fetch = [&](int kt) {
#pragma unroll
    for (int i = 0; i < 2; ++i) {
      int c = c0 + i;
      int row = c >> 2, kc = c & 3;
      pa[i] = *(const float4*)&A [(size_t)(m0 + row) * K + kt * 32 + kc * 8];
      pb[i] = *(const float4*)&Bw[(size_t)(n0 + row) * K + kt * 32 + kc * 8];
    }
  };

  f32x4 acc[4][4] = {};
  fetch(0);
  for (int kt = 0; kt < NT; ++kt) {
    __syncthreads();
#pragma unroll
    for (int i = 0; i < 2; ++i) {
      int c = c0 + i;
      *(float4*)&As[c * 8] = pa[i];
      *(float4*)&Bs[c * 8] = pb[i];
    }
    __syncthreads();
    if (kt + 1 < NT) fetch(kt + 1);
    f16x8 af[4], bf[4];
#pragma unroll
    for (int i = 0; i < 4; ++i) {
      af[i] = *(const f16x8*)&As[(mw + i * 16 + (lane & 15)) * 32 + (lane >> 4) * 8];
      bf[i] = *(const f16x8*)&Bs[(nw + i * 16 + (lane & 15)) * 32 + (lane >> 4) * 8];
    }
#pragma unroll
    for (int i = 0; i < 4; ++i)
#pragma unroll
      for (int j = 0; j < 4; ++j)
        acc[i][j] = __builtin_amdgcn_mfma_f32_16x16x32_f16(af[i], bf[j], acc[i][j], 0, 0, 0);
  }

#pragma unroll
  for (int j = 0; j < 4; ++j) {
    int col = n0 + nw + j * 16 + (lane & 15);
    float bv = bias[col];
#pragma unroll
    for (int i = 0; i < 4; ++i) {
#pragma unroll
      for (int r = 0; r < 4; ++r) {
        int row = m0 + mw + i * 16 + (lane >> 4) * 4 + r;
        if (row < Mvalid) C[(size_t)row * N + col] = (f16)(acc[i][j][r] + bv);
      }
    }
  }
}

// ---------------- persistent recurrence kernel (dataflow flags, no global barrier) ----
// r11 structure (PASSED) with the phase-A h-wait narrowed to the 32 wgs that
// produce this wave's K-half (dims [kh*512,+512) <- heads 4kh..4kh+3 <- wgs
// [32kh,32kh+32)). The pbuf __syncthreads joins BOTH halves before any fg
// store, so fg stores remain gated on all 64 Bfl >= t-1 — the single-buffer
// fgbuf and h-parity safety proofs of r11 are unchanged.
__global__ __launch_bounds__(512, 2)
void k_rec(const f16* __restrict__ Wh16, const float* __restrict__ bh,
           const f16* __restrict__ v16,  const f16* __restrict__ x2fg,
           f16* __restrict__ hfrag, float* __restrict__ fgbuf,
           f16* __restrict__ hs_out, float* __restrict__ out_packed,
           float* __restrict__ hn_out,
           const int* __restrict__ inv, const int* __restrict__ lgt,
           int* __restrict__ Afl, int* __restrict__ Bfl, int epoch0)
{
  __shared__ __align__(16) f16   Wlds[32 * 2 * 64 * 8];  // 64 KB [kk][ct][lane][8]
  __shared__ __align__(16) f16x4 Rq[32 * 64];            // 16 KB
  __shared__ __align__(16) f16x4 Uq[16 * 2 * 64];        // 16 KB
  __shared__ __align__(16) f32x4 pbuf[8][64];            // 8 KB: half-K partial tiles
  __shared__ __align__(16) float fbuf[8][128];           // 4 KB (wave-private rows)
  __shared__ __align__(16) float abuf[8][64];            // 2 KB (wave-private rows)

  const int tid  = threadIdx.x;
  const int lane = tid & 63;
  const int wave = tid >> 6;
  const int wg   = blockIdx.x;
  const int cs   = wg;                   // col-slice: cols cs*32 .. cs*32+32
  const int rt   = wave & 3;             // row tile 0..3
  const int kh   = wave >> 2;            // K-half 0/1
  const int nh   = wg >> 3;
  const int b    = ((wg & 7) << 3) + wave;
  const int cf   = nh * HD_;

  // stage full-K Wh slice (32 cols) into LDS in MFMA B-fragment layout
  for (int i = tid; i < 32 * 2 * 64; i += 512) {
    int kk = i >> 7;
    int nt = (i >> 6) & 1;
    int ln = i & 63;
    int col = cs * 32 + nt * 16 + (ln & 15);
    int kg  = kk * 32 + (ln >> 4) * 8;
    *(float4*)&Wlds[(size_t)i * 8] = *(const float4*)&Wh16[(size_t)col * HH + kg];
  }
  // role basis -> LDS
  for (int e = tid; e < 32 * 64; e += 512) {
    int i = e >> 6, role = e & 63;
    Rq[e] = *(const f16x4*)&v16[(size_t)role * H2 + nh * 256 + 4 * i];
  }
  // unbind basis -> LDS
  for (int e = tid; e < 16 * 2 * 64; e += 512) {
    int i = e >> 7, half = (e >> 6) & 1, l = e & 63;
    int r0 = 4 * i + 2 * half;
    const f16* u0 = &v16[(size_t)r0 * H2 + nh * 256 + 128 + 2 * l];
    const f16* u1 = &v16[(size_t)(r0 + 1) * H2 + nh * 256 + 128 + 2 * l];
    f16x4 tv; tv.x = u0[0]; tv.y = u0[1]; tv.z = u1[0]; tv.w = u1[1];
    Uq[e] = tv;
  }
  __syncthreads();

  const int d0 = cf + 2 * lane;
  const float2 bf2 = *(const float2*)&bh[d0];
  const float2 bg2 = *(const float2*)&bh[HH + d0];
  const int lb = lgt[b];
  float ho0 = 0.f, ho1 = 0.f;
  // fg producer flags for head nh: f = slices 4nh..4nh+3, g = slices 32+4nh..+3
  const int pidx = (lane < 4) ? (4 * nh + lane)
                 : (lane < 8) ? (28 + 4 * nh + lane)   // 32 + 4nh + (lane-4)
                 : wg;                                 // benign dummy
  // this wave's h-producer flag index: wgs [32kh, 32kh+32), each lane covers one
  const int hidx = 32 * kh + (lane & 31);
  // h fragment stream base (within one parity buffer):
  const size_t hoff = (((size_t)kh * 64 + rt) * 64 + lane) * 16;
  const char* hbase0 = (const char*)hfrag;                          // parity 0
  const char* hbase1 = (const char*)hfrag + (size_t)BB * HH * 2;    // parity 1
  unsigned* hw32 = (unsigned*)hfrag;
  const size_t hui = ((((size_t)(d0 >> 5) * 4 + (b >> 4)) * 64
                      + ((b & 15) + (((d0 >> 3) & 3) << 4))) * 4 + ((d0 & 7) >> 1));
  const char* fp  = (const char*)fgbuf + (((size_t)b * H2) + d0) * 4;
  const char* gp  = fp + (size_t)HH * 4;

  for (int t = 0; t < TT; ++t) {
    const int e = epoch0 + t + 1;
    const size_t row = (size_t)t * BB + b;
    // ---- prefetch phase-B inputs (cached; consumed after fg wait) ----
    const f16* xr = x2fg + row * H2;
    f16x2 xf = *(const f16x2*)&xr[d0];
    f16x2 xg = *(const f16x2*)&xr[HH + d0];
    int   p  = inv[row];

    // ---- wait: h(t-1) for THIS K-half only (32 producer wgs) ----
    for (;;) {
      int v = ALOAD32(&Bfl[hidx]);
      if (__all(v >= e - 1)) break;
      __builtin_amdgcn_s_sleep(1);
    }

    // ---------- phase A: K-half partials for both ct tiles ----------
    f32x4 acc0 = {0.f, 0.f, 0.f, 0.f}, acc1 = acc0;
    {
      const char* hb0 = ((t & 1) ? hbase0 : hbase1) + hoff;   // read parity (t+1)&1
      float4 hb[16];
#pragma unroll
      for (int j = 0; j < 16; ++j) {
        asm volatile("global_load_dwordx4 %0, %1, off sc0 sc1"
                     : "=v"(hb[j]) : "v"(hb0 + (size_t)j * 4096));
      }
      asm volatile("s_waitcnt vmcnt(0)" ::: "memory");
      __builtin_amdgcn_sched_barrier(0);
#pragma unroll
      for (int j = 0; j < 16; ++j) {
        int kk = kh * 16 + j;
        f16x8 af = __builtin_bit_cast(f16x8, hb[j]);
        f16x8 b0 = *(const f16x8*)&Wlds[((kk * 2 + 0) * 64 + lane) * 8];
        f16x8 b1 = *(const f16x8*)&Wlds[((kk * 2 + 1) * 64 + lane) * 8];
        acc0 = __builtin_amdgcn_mfma_f32_16x16x32_f16(af, b0, acc0, 0, 0, 0);
        acc1 = __builtin_amdgcn_mfma_f32_16x16x32_f16(af, b1, acc1, 0, 0, 0);
      }
    }
    // half-K reduction: wave (rt,kh) finalizes ct==kh; stores the other partial.
    // This rendezvous joins BOTH halves => fg stores below are all-64 gated.
    pbuf[wave][lane] = (kh == 0) ? acc1 : acc0;
    __syncthreads();
    {
      f32x4 acc = ((kh == 0) ? acc0 : acc1) + pbuf[wave ^ 4][lane];
      const int col = cs * 32 + kh * 16 + (lane & 15);
      const int r0  = rt * 16 + (lane >> 4) * 4;
#pragma unroll
      for (int r = 0; r < 4; ++r) ASTORE(&fgbuf[(size_t)(r0 + r) * H2 + col], acc[r]);
    }
    __syncthreads();                 // drain all waves' fg stores (vmcnt0 before barrier)
    if (tid == 0) ASTORE(&Afl[wg], e);

    // ---- wait: this head's 8 fg producers done ----
    for (;;) {
      int v = ALOAD32(&Afl[pidx]);
      if (__all((lane >= 8) | (v >= e))) break;
      __builtin_amdgcn_s_sleep(1);
    }

    // ---------- phase B ----------
    float2 fv, gv;
    asm volatile("global_load_dwordx2 %0, %1, off sc0 sc1" : "=v"(fv) : "v"(fp));
    asm volatile("global_load_dwordx2 %0, %1, off sc0 sc1" : "=v"(gv) : "v"(gp));
    asm volatile("s_waitcnt vmcnt(0)" ::: "memory");
    __builtin_amdgcn_sched_barrier(0);
    float f0 = fv.x + bf2.x + (float)xf.x;
    float f1 = fv.y + bf2.y + (float)xf.y;
    float g0 = gv.x + bg2.x + (float)xg.x;
    float g1 = gv.y + bg2.y + (float)xg.y;
    *(float2*)&fbuf[wave][2 * lane] = make_float2(f0, f1);
    float s = 0.f;
#pragma unroll
    for (int i = 0; i < 32; ++i) {
      float4 fvv = *(const float4*)&fbuf[wave][4 * i];
      f16x4 rv = Rq[i * 64 + lane];
      s = fmaf(fvv.x, (float)rv.x, s);
      s = fmaf(fvv.y, (float)rv.y, s);
      s = fmaf(fvv.z, (float)rv.z, s);
      s = fmaf(fvv.w, (float)rv.w, s);
    }
    float mx = s;
#pragma unroll
    for (int off = 32; off > 0; off >>= 1) mx = fmaxf(mx, __shfl_xor(mx, off));
    float e2 = expf(s - mx);
    float sum = e2;
#pragma unroll
    for (int off = 32; off > 0; off >>= 1) sum += __shfl_xor(sum, off);
    abuf[wave][lane] = e2 / sum;
    float bd0 = 0.f, bd1 = 0.f;
#pragma unroll
    for (int i = 0; i < 16; ++i) {
      float4 av = *(const float4*)&abuf[wave][4 * i];
      f16x4 u01 = Uq[(i * 2 + 0) * 64 + lane];
      f16x4 u23 = Uq[(i * 2 + 1) * 64 + lane];
      bd0 = fmaf(av.x, (float)u01.x, bd0); bd1 = fmaf(av.x, (float)u01.y, bd1);
      bd0 = fmaf(av.y, (float)u01.z, bd0); bd1 = fmaf(av.y, (float)u01.w, bd1);
      bd0 = fmaf(av.z, (float)u23.x, bd0); bd1 = fmaf(av.z, (float)u23.y, bd1);
      bd0 = fmaf(av.w, (float)u23.z, bd0); bd1 = fmaf(av.w, (float)u23.w, bd1);
    }
    float gt0 = 1.f / (1.f + expf(-g0));
    float gt1 = 1.f / (1.f + expf(-g1));
    float hv0 = gt0 * tanhf(bd0) + (1.f - gt0) * ho0;
    float hv1 = gt1 * tanhf(bd1) + (1.f - gt1) * ho1;
    ho0 = hv0; ho1 = hv1;
    {
      unsigned hp = (unsigned)__builtin_bit_cast(unsigned short, (f16)hv0)
                  | ((unsigned)__builtin_bit_cast(unsigned short, (f16)hv1) << 16);
      ASTORE(hw32 + (size_t)(t & 1) * (BB * HH / 2) + hui, hp);   // parity t&1
    }
    __syncthreads();                 // drain all waves' h stores
    if (tid == 0) ASTORE(&Bfl[wg], e);

    // ---- deferred output writes: overlap with other wgs' polling ----
    if (hs_out) {
      f16x2 hp2; hp2.x = (f16)ho0; hp2.y = (f16)ho1;
      *(f16x2*)&hs_out[row * HH + d0] = hp2;
    }
    if (out_packed && p >= 0) {
      *(float2*)&out_packed[(size_t)p * HH + d0] = make_float2(ho0, ho1);
    }
    if (lb == t + 1) {
      *(float2*)&hn_out[(size_t)b * HH + d0] = make_float2(ho0, ho1);
    }
  }
}

// ---------------- host ----------------
extern "C" void kernel_launch(void* const* d_in, const int* in_sizes, int n_in,
                              void* d_out, int out_size, void* d_ws, size_t ws_size,
                              hipStream_t stream) {
  const float* x      = (const float*)d_in[0];
  const int*   idx    = (const int*)d_in[1];
  const int*   lgt    = (const int*)d_in[2];
  const float* basis0 = (const float*)d_in[3];
  const float* basis1 = (const float*)d_in[4];
  const float* Wx0 = (const float*)d_in[5];  const float* bx0 = (const float*)d_in[6];
  const float* Wh0 = (const float*)d_in[7];  const float* bh0 = (const float*)d_in[8];
  const float* Wv0 = (const float*)d_in[9];  const float* bv0 = (const float*)d_in[10];
  const float* Wx1 = (const float*)d_in[11]; const float* bx1 = (const float*)d_in[12];
  const float* Wh1 = (const float*)d_in[13]; const float* bh1 = (const float*)d_in[14];
  const float* Wv1 = (const float*)d_in[15]; const float* bv1 = (const float*)d_in[16];
  const int total = in_sizes[1];

  char* ws = (char*)d_ws;
  size_t off = 0;
  auto alloc = [&](size_t bytes) -> void* {
    void* p = (void*)(ws + off);
    off += (bytes + 255) & ~(size_t)255;
    return p;
  };

  int*   Afl     = (int*)alloc(RWG * 4);
  int*   Bfl     = (int*)alloc(RWG * 4);
  int*   inv     = (int*)alloc((size_t)MROWS * 4);
  f16*   xpad    = (f16*)alloc((size_t)MROWS * DD * 2);
  f16*   x2fg    = (f16*)alloc((size_t)MROWS * H2 * 2);
  f16*   hfrag   = (f16*)alloc((size_t)2 * BB * HH * 2);   // parity double-buffer
  float* fgbuf   = (float*)alloc((size_t)BB * H2 * 4);
  f16* Wx0h = (f16*)alloc((size_t)H2 * DD * 2);
  f16* Wh0h = (f16*)alloc((size_t)H2 * HH * 2);
  f16* Wv0h = (f16*)alloc((size_t)H2 * HH * 2);
  f16* Wx1h = (f16*)alloc((size_t)H2 * HH * 2);
  f16* Wh1h = (f16*)alloc((size_t)H2 * HH * 2);
  f16* Wv1h = (f16*)alloc((size_t)H2 * HH * 2);
  f16* bas0h = (f16*)alloc((size_t)128 * HH * 2);
  f16* bas1h = (f16*)alloc((size_t)128 * HH * 2);
  f16* v0h = (f16*)alloc((size_t)NR_ * H2 * 2);
  f16* v1h = (f16*)alloc((size_t)NR_ * H2 * 2);

  float* out = (float*)d_out;
  float* hn0 = out + (size_t)total * HH;
  float* hn1 = hn0 + (size_t)BB * HH;
  f16* hs0 = (f16*)d_out;   // layer-0 hidden stash (64 MB), dead before layer-1 output

  (void)hipMemsetAsync(Afl, 0, RWG * 4, stream);
  (void)hipMemsetAsync(Bfl, 0, RWG * 4, stream);
  (void)hipMemsetAsync(inv, 0xFF, (size_t)MROWS * 4, stream);
  (void)hipMemsetAsync(xpad, 0, (size_t)MROWS * DD * 2, stream);
  (void)hipMemsetAsync(bas0h, 0, (size_t)128 * HH * 2, stream);
  (void)hipMemsetAsync(bas1h, 0, (size_t)128 * HH * 2, stream);
  (void)hipMemsetAsync(hfrag, 0, (size_t)2 * BB * HH * 2, stream);

  k_cvt<<<512, 256, 0, stream>>>(Wx0, Wx0h, H2 * DD);
  k_cvt<<<512, 256, 0, stream>>>(Wh0, Wh0h, H2 * HH);
  k_cvt<<<512, 256, 0, stream>>>(Wv0, Wv0h, H2 * HH);
  k_cvt<<<512, 256, 0, stream>>>(Wx1, Wx1h, H2 * HH);
  k_cvt<<<512, 256, 0, stream>>>(Wh1, Wh1h, H2 * HH);
  k_cvt<<<512, 256, 0, stream>>>(Wv1, Wv1h, H2 * HH);
  k_cvt<<<64, 256, 0, stream>>>(basis0, bas0h, NR_ * HH);
  k_cvt<<<64, 256, 0, stream>>>(basis1, bas1h, NR_ * HH);
  k_scatter<<<2048, 256, 0, stream>>>(x, idx, xpad, total);
  k_inv<<<(total + 255) / 256, 256, 0, stream>>>(idx, inv, total);

  dim3 gv(16, 1);
  k_gemm<<<gv, 256, 0, stream>>>(bas0h, Wv0h, bv0, v0h, H2, HH, NR_);
  k_gemm<<<gv, 256, 0, stream>>>(bas1h, Wv1h, bv1, v1h, H2, HH, NR_);

  dim3 gx(H2 / 128, MROWS / 128);
  k_gemm<<<gx, 256, 0, stream>>>(xpad, Wx0h, bx0, x2fg, H2, DD, MROWS);

  k_rec<<<RWG, 512, 0, stream>>>(Wh0h, bh0, v0h, x2fg, hfrag, fgbuf,
                                 hs0, nullptr, hn0, inv, lgt, Afl, Bfl, 0);

  (void)hipMemsetAsync(hfrag, 0, (size_t)2 * BB * HH * 2, stream);

  k_gemm<<<gx, 256, 0, stream>>>(hs0, Wx1h, bx1, x2fg, H2, HH, MROWS);

  k_rec<<<RWG, 512, 0, stream>>>(Wh1h, bh1, v1h, x2fg, hfrag, fgbuf,
                                 nullptr, out, hn1, inv, lgt, Afl, Bfl, TT);
}